// Round 1
// baseline (79.738 us; speedup 1.0000x reference)
//
#include <hip/hip_runtime.h>

// NgramMinPooling: B=32, S=2048, H=512, N_GRAM=3, float32.
// out[row] = row in rand_index ? blend(min(x[row],x[row-1],x[row-2] within batch), x[row])
//                              : blend(x[row], x[row])  == x[row] (we blend uniformly; diff ~1 ulp)
// blend(m, v) = sigmoid(v)*m + (1-sigmoid(v))*v

#define S_LEN 2048
#define H_LEN 512

__global__ __launch_bounds__(128)
void ngram_min_pool(const float* __restrict__ x,
                    const int* __restrict__ idx,
                    int n_idx,
                    float* __restrict__ out)
{
    const int row = blockIdx.x;          // 0 .. B*S-1
    const int tid = threadIdx.x;         // 0 .. 127, one float4 each
    const int s   = row & (S_LEN - 1);   // position within sequence

    // Binary search: is `row` in the sorted index list? (uniform across block)
    int lo = 0, hi = n_idx;
    while (lo < hi) {
        int mid = (lo + hi) >> 1;
        if (idx[mid] < row) lo = mid + 1; else hi = mid;
    }
    const bool selected = (lo < n_idx) && (idx[lo] == row);

    const size_t base = (size_t)row * H_LEN;
    const float4 v0 = reinterpret_cast<const float4*>(x + base)[tid];
    float4 m = v0;

    if (selected) {
        float4 v1 = make_float4(0.f, 0.f, 0.f, 0.f);
        float4 v2 = make_float4(0.f, 0.f, 0.f, 0.f);
        if (s >= 1) v1 = reinterpret_cast<const float4*>(x + base - H_LEN)[tid];
        if (s >= 2) v2 = reinterpret_cast<const float4*>(x + base - 2 * H_LEN)[tid];
        m.x = fminf(v0.x, fminf(v1.x, v2.x));
        m.y = fminf(v0.y, fminf(v1.y, v2.y));
        m.z = fminf(v0.z, fminf(v1.z, v2.z));
        m.w = fminf(v0.w, fminf(v1.w, v2.w));
    }

    float4 r;
    {
        const float gx = 1.0f / (1.0f + __expf(-v0.x));
        const float gy = 1.0f / (1.0f + __expf(-v0.y));
        const float gz = 1.0f / (1.0f + __expf(-v0.z));
        const float gw = 1.0f / (1.0f + __expf(-v0.w));
        r.x = gx * m.x + (1.0f - gx) * v0.x;
        r.y = gy * m.y + (1.0f - gy) * v0.y;
        r.z = gz * m.z + (1.0f - gz) * v0.z;
        r.w = gw * m.w + (1.0f - gw) * v0.w;
    }
    reinterpret_cast<float4*>(out + base)[tid] = r;
}

extern "C" void kernel_launch(void* const* d_in, const int* in_sizes, int n_in,
                              void* d_out, int out_size, void* d_ws, size_t ws_size,
                              hipStream_t stream)
{
    const float* x   = (const float*)d_in[0];
    const int*   idx = (const int*)d_in[1];
    const int n_idx  = in_sizes[1];
    float* out = (float*)d_out;

    const int n_rows = in_sizes[0] / H_LEN;   // B*S = 65536
    ngram_min_pool<<<n_rows, 128, 0, stream>>>(x, idx, n_idx, out);
}

// Round 2
// 64.157 us; speedup vs baseline: 1.2428x; 1.2428x over previous
//
#include <hip/hip_runtime.h>

// NgramMinPooling: B=32, S=2048, H=512, N_GRAM=3, float32.
// Row r selected (r in sorted rand_index):
//   m = min(x[r], x[r-1], x[r-2])  (within batch; missing rows treated as 0)
// else m = x[r].
// out = sigmoid(x)*m + (1-sigmoid(x))*x
//
// Two-phase: (1) scatter per-row selection flags into d_ws (removes the
// per-block serial binary search that made round-1 latency-bound),
// (2) near-copy main kernel at HBM BW.

#define S_LEN 2048
#define H_LEN 512
#define ROWS_PER_BLOCK 2   // 256 threads, 128 per row (one float4 each)

__global__ __launch_bounds__(256)
void scatter_flags(const int* __restrict__ idx, int n_idx,
                   unsigned char* __restrict__ flags)
{
    int i = blockIdx.x * 256 + threadIdx.x;
    if (i < n_idx) flags[idx[i]] = 1;
}

__global__ __launch_bounds__(256)
void ngram_min_pool(const float* __restrict__ x,
                    const unsigned char* __restrict__ flags,
                    float* __restrict__ out)
{
    const int tid = threadIdx.x;
    const int row = blockIdx.x * ROWS_PER_BLOCK + (tid >> 7); // 2 rows/block
    const int lane128 = tid & 127;                            // float4 slot in row
    const int s = row & (S_LEN - 1);

    const bool selected = flags[row] != 0;

    const size_t base = (size_t)row * H_LEN;
    const float4 v0 = reinterpret_cast<const float4*>(x + base)[lane128];
    float4 m = v0;

    if (selected) {
        float4 v1 = make_float4(0.f, 0.f, 0.f, 0.f);
        float4 v2 = make_float4(0.f, 0.f, 0.f, 0.f);
        if (s >= 1) v1 = reinterpret_cast<const float4*>(x + base - H_LEN)[lane128];
        if (s >= 2) v2 = reinterpret_cast<const float4*>(x + base - 2 * H_LEN)[lane128];
        m.x = fminf(v0.x, fminf(v1.x, v2.x));
        m.y = fminf(v0.y, fminf(v1.y, v2.y));
        m.z = fminf(v0.z, fminf(v1.z, v2.z));
        m.w = fminf(v0.w, fminf(v1.w, v2.w));
    }

    float4 r;
    const float gx = 1.0f / (1.0f + __expf(-v0.x));
    const float gy = 1.0f / (1.0f + __expf(-v0.y));
    const float gz = 1.0f / (1.0f + __expf(-v0.z));
    const float gw = 1.0f / (1.0f + __expf(-v0.w));
    r.x = gx * m.x + (1.0f - gx) * v0.x;
    r.y = gy * m.y + (1.0f - gy) * v0.y;
    r.z = gz * m.z + (1.0f - gz) * v0.z;
    r.w = gw * m.w + (1.0f - gw) * v0.w;

    reinterpret_cast<float4*>(out + base)[lane128] = r;
}

extern "C" void kernel_launch(void* const* d_in, const int* in_sizes, int n_in,
                              void* d_out, int out_size, void* d_ws, size_t ws_size,
                              hipStream_t stream)
{
    const float* x   = (const float*)d_in[0];
    const int*   idx = (const int*)d_in[1];
    const int n_idx  = in_sizes[1];
    float* out = (float*)d_out;

    const int n_rows = in_sizes[0] / H_LEN;   // B*S = 65536
    unsigned char* flags = (unsigned char*)d_ws;

    hipMemsetAsync(flags, 0, n_rows, stream);
    scatter_flags<<<(n_idx + 255) / 256, 256, 0, stream>>>(idx, n_idx, flags);
    ngram_min_pool<<<n_rows / ROWS_PER_BLOCK, 256, 0, stream>>>(x, flags, out);
}

// Round 3
// 50.755 us; speedup vs baseline: 1.5710x; 1.2641x over previous
//
#include <hip/hip_runtime.h>

// NgramMinPooling: B=32, S=2048, H=512, N_GRAM=3, float32.
// Row r selected (r in sorted rand_index):
//   m = min(x[r], x[r-1], x[r-2])  (within batch; rows shifted past the
//   batch start contribute 0)
// else m = x[r].
// out = sigmoid(x)*m + (1-sigmoid(x))*x
//
// Three tiny phases, all in one graph:
//  (0) zero 64 KB of row flags in d_ws          (16 blocks)
//  (1) scatter flags[idx[i]] = 1                (180 blocks)
//  (2) main near-copy kernel at HBM BW:
//      - 1024 threads = 8 rows/block -> neighbor-row reads are L1 hits
//        except at block boundaries
//      - XCD-contiguous block swizzle so boundary reads hit same-XCD L2

#define S_LEN 2048
#define H_LEN 512
#define ROWS_PER_BLOCK 8          // 1024 threads, 128 per row (one float4 each)

__global__ __launch_bounds__(256)
void zero_flags(uint4* __restrict__ flags)   // 64 KiB = 4096 uint4
{
    flags[blockIdx.x * 256 + threadIdx.x] = make_uint4(0u, 0u, 0u, 0u);
}

__global__ __launch_bounds__(256)
void scatter_flags(const int* __restrict__ idx, int n_idx,
                   unsigned char* __restrict__ flags)
{
    int i = blockIdx.x * 256 + threadIdx.x;
    if (i < n_idx) flags[idx[i]] = 1;
}

__global__ __launch_bounds__(1024)
void ngram_min_pool(const float* __restrict__ x,
                    const unsigned char* __restrict__ flags,
                    float* __restrict__ out,
                    int nwg)
{
    // XCD-contiguous swizzle: XCD k owns blocks [k*nwg/8, (k+1)*nwg/8)
    // -> contiguous rows, so cross-block neighbor reads hit same-XCD L2.
    int bid = blockIdx.x;
    const int cpx = nwg >> 3;               // nwg % 8 == 0 (8192)
    bid = (bid & 7) * cpx + (bid >> 3);

    const int tid  = threadIdx.x;
    const int row  = bid * ROWS_PER_BLOCK + (tid >> 7);
    const int lane = tid & 127;             // float4 slot within the row
    const int s    = row & (S_LEN - 1);     // position within sequence

    const bool selected = flags[row] != 0;

    const size_t base = (size_t)row * H_LEN;
    const float4 v0 = reinterpret_cast<const float4*>(x + base)[lane];
    float4 m = v0;

    if (selected) {
        float4 v1 = make_float4(0.f, 0.f, 0.f, 0.f);
        float4 v2 = make_float4(0.f, 0.f, 0.f, 0.f);
        if (s >= 1) v1 = reinterpret_cast<const float4*>(x + base - H_LEN)[lane];
        if (s >= 2) v2 = reinterpret_cast<const float4*>(x + base - 2 * H_LEN)[lane];
        m.x = fminf(v0.x, fminf(v1.x, v2.x));
        m.y = fminf(v0.y, fminf(v1.y, v2.y));
        m.z = fminf(v0.z, fminf(v1.z, v2.z));
        m.w = fminf(v0.w, fminf(v1.w, v2.w));
    }

    float4 r;
    const float gx = 1.0f / (1.0f + __expf(-v0.x));
    const float gy = 1.0f / (1.0f + __expf(-v0.y));
    const float gz = 1.0f / (1.0f + __expf(-v0.z));
    const float gw = 1.0f / (1.0f + __expf(-v0.w));
    r.x = gx * m.x + (1.0f - gx) * v0.x;
    r.y = gy * m.y + (1.0f - gy) * v0.y;
    r.z = gz * m.z + (1.0f - gz) * v0.z;
    r.w = gw * m.w + (1.0f - gw) * v0.w;

    reinterpret_cast<float4*>(out + base)[lane] = r;
}

extern "C" void kernel_launch(void* const* d_in, const int* in_sizes, int n_in,
                              void* d_out, int out_size, void* d_ws, size_t ws_size,
                              hipStream_t stream)
{
    const float* x   = (const float*)d_in[0];
    const int*   idx = (const int*)d_in[1];
    const int n_idx  = in_sizes[1];
    float* out = (float*)d_out;

    const int n_rows = in_sizes[0] / H_LEN;   // B*S = 65536
    unsigned char* flags = (unsigned char*)d_ws;

    zero_flags<<<n_rows / (256 * 16), 256, 0, stream>>>((uint4*)flags);
    scatter_flags<<<(n_idx + 255) / 256, 256, 0, stream>>>(idx, n_idx, flags);

    const int nwg = n_rows / ROWS_PER_BLOCK;  // 8192
    ngram_min_pool<<<nwg, 1024, 0, stream>>>(x, flags, out, nwg);
}

// Round 5
// 47.192 us; speedup vs baseline: 1.6897x; 1.0755x over previous
//
#include <hip/hip_runtime.h>

// NgramMinPooling: B=32, S=2048, H=512, N_GRAM=3, float32.
// Row r selected (r in sorted rand_index):
//   m = min(x[r], x[r-1], x[r-2])  (within batch; rows shifted past the
//   batch start contribute 0)
// else m = x[r].
// out = sigmoid(x)*m + (1-sigmoid(x))*x
//
// Two dispatches:
//  (1) build_flags: idx is sorted+unique, so thread i sets flags[idx[i]]=1
//      and zeros the gap to idx[i+1] (mean gap 1.43). Fuses the old
//      zero+scatter pair -> one launch, no pre-memset.
//  (2) main near-copy kernel at HBM BW:
//      - 1024 threads = 8 rows/block -> neighbor-row reads are L1 hits
//        except at block boundaries
//      - XCD-contiguous block swizzle so boundary reads hit same-XCD L2
//      - nontemporal float4 stores (via clang ext_vector type; the builtin
//        rejects HIP_vector_type): out is write-once, keep it out of L2

#define S_LEN 2048
#define H_LEN 512
#define ROWS_PER_BLOCK 8          // 1024 threads, 128 per row (one float4 each)

typedef float f32x4 __attribute__((ext_vector_type(4)));

__global__ __launch_bounds__(256)
void build_flags(const int* __restrict__ idx, int n_idx, int n_rows,
                 unsigned char* __restrict__ flags)
{
    int i = blockIdx.x * 256 + threadIdx.x;
    if (i >= n_idx) return;
    const int cur = idx[i];
    flags[cur] = 1;
    const int next = (i + 1 < n_idx) ? idx[i + 1] : n_rows;
    for (int k = cur + 1; k < next; ++k) flags[k] = 0;
    if (i == 0)
        for (int k = 0; k < cur; ++k) flags[k] = 0;
}

__global__ __launch_bounds__(1024)
void ngram_min_pool(const float* __restrict__ x,
                    const unsigned char* __restrict__ flags,
                    float* __restrict__ out,
                    int nwg)
{
    // XCD-contiguous swizzle: XCD k owns blocks [k*nwg/8, (k+1)*nwg/8)
    int bid = blockIdx.x;
    const int cpx = nwg >> 3;               // nwg % 8 == 0 (8192)
    bid = (bid & 7) * cpx + (bid >> 3);

    const int tid  = threadIdx.x;
    const int row  = bid * ROWS_PER_BLOCK + (tid >> 7);
    const int lane = tid & 127;             // float4 slot within the row
    const int s    = row & (S_LEN - 1);     // position within sequence

    const bool selected = flags[row] != 0;

    const size_t base = (size_t)row * H_LEN;
    const f32x4 v0 = reinterpret_cast<const f32x4*>(x + base)[lane];
    f32x4 m = v0;

    if (selected) {
        f32x4 v1 = (f32x4)(0.f);
        f32x4 v2 = (f32x4)(0.f);
        if (s >= 1) v1 = reinterpret_cast<const f32x4*>(x + base - H_LEN)[lane];
        if (s >= 2) v2 = reinterpret_cast<const f32x4*>(x + base - 2 * H_LEN)[lane];
        m.x = fminf(v0.x, fminf(v1.x, v2.x));
        m.y = fminf(v0.y, fminf(v1.y, v2.y));
        m.z = fminf(v0.z, fminf(v1.z, v2.z));
        m.w = fminf(v0.w, fminf(v1.w, v2.w));
    }

    f32x4 r;
    const float gx = 1.0f / (1.0f + __expf(-v0.x));
    const float gy = 1.0f / (1.0f + __expf(-v0.y));
    const float gz = 1.0f / (1.0f + __expf(-v0.z));
    const float gw = 1.0f / (1.0f + __expf(-v0.w));
    r.x = gx * m.x + (1.0f - gx) * v0.x;
    r.y = gy * m.y + (1.0f - gy) * v0.y;
    r.z = gz * m.z + (1.0f - gz) * v0.z;
    r.w = gw * m.w + (1.0f - gw) * v0.w;

    __builtin_nontemporal_store(r, reinterpret_cast<f32x4*>(out + base) + lane);
}

extern "C" void kernel_launch(void* const* d_in, const int* in_sizes, int n_in,
                              void* d_out, int out_size, void* d_ws, size_t ws_size,
                              hipStream_t stream)
{
    const float* x   = (const float*)d_in[0];
    const int*   idx = (const int*)d_in[1];
    const int n_idx  = in_sizes[1];
    float* out = (float*)d_out;

    const int n_rows = in_sizes[0] / H_LEN;   // B*S = 65536
    unsigned char* flags = (unsigned char*)d_ws;

    build_flags<<<(n_idx + 255) / 256, 256, 0, stream>>>(idx, n_idx, n_rows, flags);

    const int nwg = n_rows / ROWS_PER_BLOCK;  // 8192
    ngram_min_pool<<<nwg, 1024, 0, stream>>>(x, flags, out, nwg);
}